// Round 5
// baseline (244.158 us; speedup 1.0000x reference)
//
#include <hip/hip_runtime.h>

#define B_  4
#define L_  4096
#define D_  2048
#define HD_ 128
#define M_  (B_*L_)   // 16384

typedef __attribute__((ext_vector_type(8))) short short8;
typedef __attribute__((ext_vector_type(4))) float f32x4;
typedef __attribute__((ext_vector_type(4))) unsigned short u16x4;
typedef __attribute__((ext_vector_type(4))) unsigned int u32x4;
typedef unsigned short u16;

#define GLL16(g, l) __builtin_amdgcn_global_load_lds( \
    (const __attribute__((address_space(1))) void*)(g), \
    (__attribute__((address_space(3))) void*)(l), 16, 0, 0)

__device__ __forceinline__ u16 f2bf(float f){
  union { float f; unsigned u; } v; v.f = f;
  unsigned r = v.u + 0x7FFFu + ((v.u >> 16) & 1u);
  return (u16)(r >> 16);
}

__device__ __forceinline__ unsigned cvtpk_bf16(float a, float b){
  unsigned r;
  asm volatile("v_cvt_pk_bf16_f32 %0, %1, %2" : "=v"(r) : "v"(a), "v"(b));
  return r;
}

// ---------------- prep: weight transposes to bf16 (weights only) ----------
__global__ __launch_bounds__(256) void prep_kernel(
    const float* __restrict__ Wq, const float* __restrict__ Wk,
    const float* __restrict__ Wv, const float* __restrict__ Wo,
    u16* __restrict__ Wt_qkv, u16* __restrict__ Wt_o)
{
  __shared__ float T[64][68];
  const int tid = threadIdx.x;
  int tb = blockIdx.x;                 // 0..255
  int mat = tb >> 6, t = tb & 63;
  const float* src; u16* dst; int Rw, Cw, rt, ct;
  if (mat < 3) {
    src = (mat==0) ? Wq : (mat==1) ? Wk : Wv;
    dst = Wt_qkv + (size_t)mat*HD_*D_;
    Rw = D_; Cw = HD_; rt = t >> 1; ct = t & 1;
  } else {
    src = Wo; dst = Wt_o;
    Rw = HD_; Cw = D_; rt = t >> 5; ct = t & 31;
  }
  int r0 = rt*64, c0 = ct*64;
  #pragma unroll
  for (int i=0;i<4;i++){
    int fid = i*256 + tid;
    int row = fid >> 4, c4 = (fid & 15) * 4;
    float4 v = *reinterpret_cast<const float4*>(src + (size_t)(r0+row)*Cw + c0 + c4);
    *reinterpret_cast<float4*>(&T[row][c4]) = v;
  }
  __syncthreads();
  #pragma unroll
  for (int i=0;i<2;i++){
    int sid = i*256 + tid;
    int crow = sid >> 3, k8 = (sid & 7) * 8;
    short8 o;
    #pragma unroll
    for (int j=0;j<8;j++) o[j] = (short)f2bf(T[k8+j][crow]);
    *reinterpret_cast<short8*>(dst + (size_t)(c0+crow)*Rw + r0 + k8) = o;
  }
}

// ---------------- fused QKV GEMM (x cast fused, x read ONCE) ---------------
// grid 256: 64 rows x 384 cols per block; 512 thr = 8 waves (2r x 4c),
// wave = 32 rows x 96 cols. A reg-staged fp32->bf16 (prefetch 1 step),
// B via global_load_lds, XOR-swizzled both sides. V stored transposed.
__global__ __launch_bounds__(512, 2) void qkv_kernel(
    const float* __restrict__ x, const u16* __restrict__ Wt,
    const float* __restrict__ bq, const float* __restrict__ bk,
    const float* __restrict__ bv,
    u16* __restrict__ Q, u16* __restrict__ K, u16* __restrict__ Vt)
{
  const int rb = blockIdx.x;          // 0..255
  const int tid  = threadIdx.x;
  const int lane = tid & 63, w = tid >> 6;
  const int wr = w >> 2, wc = w & 3;
  const int l15 = lane & 15, lhi = lane >> 4;
  const int row0 = rb * 64;

  __shared__ u16 Asm[64*64];          // x tile bf16, swizzled
  __shared__ u16 Bsm[384*64];         // Wqkv^T tile, swizzled

  // B staging: 6 GLL16 per thread, source pre-swizzled, dest linear
  const u16* bSrc[6]; u16* bDst[6];
  #pragma unroll
  for (int i=0;i<6;i++){
    int id = i*512 + w*64 + lane;
    int r = id >> 3, c = (id & 7) * 8;
    bSrc[i] = Wt + (size_t)r*D_ + (c ^ ((r&7)*8));
    bDst[i] = Bsm + i*4096 + w*512;
  }
  // A staging: 1 short8 per thread per step (2 float4 + cvt + ds_write)
  const int ar = tid >> 3, ac = (tid & 7) * 8;
  const int aoff = ar*64 + (ac ^ ((ar&7)*8));
  const float* xrow = x + (size_t)(row0+ar)*D_ + ac;

  // frag read offsets (swizzle-matched)
  int offA[2][2], offB[2][6];
  #pragma unroll
  for (int ks=0;ks<2;ks++){
    #pragma unroll
    for (int m=0;m<2;m++){
      int rA = wr*32 + m*16 + l15;
      offA[ks][m] = rA*64 + ((ks*32 + lhi*8) ^ ((rA&7)*8));
    }
    #pragma unroll
    for (int n=0;n<6;n++){
      int rB = wc*96 + n*16 + l15;
      offB[ks][n] = rB*64 + ((ks*32 + lhi*8) ^ ((rB&7)*8));
    }
  }

  f32x4 acc[2][6];
  f32x4 zero4 = {0.f,0.f,0.f,0.f};
  #pragma unroll
  for (int m=0;m<2;m++)
    #pragma unroll
    for (int n=0;n<6;n++) acc[m][n] = zero4;

  // prefetch x for k0 = 0
  float4 f0 = *reinterpret_cast<const float4*>(xrow);
  float4 f1 = *reinterpret_cast<const float4*>(xrow + 4);

  for (int k0 = 0; k0 < D_; k0 += 64) {
    __syncthreads();
    // A: cvt + swizzled ds_write
    {
      short8 a8;
      a8[0]=(short)f2bf(f0.x); a8[1]=(short)f2bf(f0.y);
      a8[2]=(short)f2bf(f0.z); a8[3]=(short)f2bf(f0.w);
      a8[4]=(short)f2bf(f1.x); a8[5]=(short)f2bf(f1.y);
      a8[6]=(short)f2bf(f1.z); a8[7]=(short)f2bf(f1.w);
      *reinterpret_cast<short8*>(Asm + aoff) = a8;
    }
    // B: 6 GLL16
    #pragma unroll
    for (int i=0;i<6;i++){ GLL16(bSrc[i], bDst[i]); bSrc[i] += 64; }
    __syncthreads();
    // prefetch x for next step (in flight during MFMA)
    if (k0 + 64 < D_) {
      const float* xp = xrow + k0 + 64;
      f0 = *reinterpret_cast<const float4*>(xp);
      f1 = *reinterpret_cast<const float4*>(xp + 4);
    }
    #pragma unroll
    for (int ks=0;ks<2;ks++){
      short8 fa[2], fb[6];
      #pragma unroll
      for (int m=0;m<2;m++) fa[m] = *reinterpret_cast<const short8*>(Asm + offA[ks][m]);
      #pragma unroll
      for (int n=0;n<6;n++) fb[n] = *reinterpret_cast<const short8*>(Bsm + offB[ks][n]);
      #pragma unroll
      for (int m=0;m<2;m++)
        #pragma unroll
        for (int n=0;n<6;n++)
          acc[m][n] = __builtin_amdgcn_mfma_f32_16x16x32_bf16(fa[m], fb[n], acc[m][n], 0, 0, 0);
    }
  }

  // epilogue
  #pragma unroll
  for (int n=0;n<6;n++){
    int col = wc*96 + n*16 + l15;
    int j = col >> 7;            // 0:Q 1:K 2:V (uniform per (wc,n))
    int c = col & 127;
    float bi = (j==0) ? bq[c] : (j==1) ? bk[c] : bv[c];
    #pragma unroll
    for (int m=0;m<2;m++){
      int rowb = row0 + wr*32 + m*16 + (lhi<<2);
      if (j < 2) {
        u16* Out = (j==0) ? Q : K;
        #pragma unroll
        for (int r=0;r<4;r++)
          Out[(size_t)(rowb+r)*HD_ + c] = f2bf(acc[m][n][r] + bi);
      } else {
        int bb = rowb >> 12;
        int l  = rowb & (L_-1);
        u16x4 v4;
        #pragma unroll
        for (int r=0;r<4;r++) v4[r] = f2bf(acc[m][n][r] + bi);
        *reinterpret_cast<u16x4*>(Vt + (size_t)bb*HD_*L_ + (size_t)c*L_ + l) = v4;
      }
    }
  }
}

// ---------------- flash attention: swapped-QK^T, in-register softmax -------
// grid 1024 (4 blocks/CU): batch -> XCD pair, work-descending 16-row strips,
// 4 waves key-split (kt = w mod 4). S^T = mfma(K,Q): lane owns q-row l15,
// softmax = in-reg tree + 2 shfl stages; P rearranged for PV via
// cvt_pk_bf16 + ds_bpermute (no LDS roundtrip). Merge via LDS at end.
__global__ __launch_bounds__(256, 4) void attn_kernel(
    const u16* __restrict__ Qg, const u16* __restrict__ Kg,
    const u16* __restrict__ Vtg, u16* __restrict__ AO)
{
  const int blk = blockIdx.x;
  const int xcd = blk & 7;
  const int sub = blk >> 3;                    // 0..127
  const int b   = xcd >> 1;                    // batch -> XCD pair
  const int strip = 255 - (2*sub + (xcd & 1)); // long strips dispatch first
  const int q0  = strip * 16;
  const int KT  = (strip >> 2) + 1;

  const int tid = threadIdx.x, lane = tid & 63, w = tid >> 6;
  const int l15 = lane & 15, lhi = lane >> 4;

  const u16* Qb  = Qg  + (size_t)b * L_ * HD_;
  const u16* Kb  = Kg  + (size_t)b * L_ * HD_;
  const u16* Vtb = Vtg + (size_t)b * HD_ * L_;

  __shared__ __attribute__((aligned(16))) float Ol[4][16][132];
  __shared__ float Ml[4][16], Ll[4][16];

  // Q fragments (B-operand now; same layout as A-operand)
  short8 qf[4];
  #pragma unroll
  for (int ks=0; ks<4; ks++)
    qf[ks] = *reinterpret_cast<const short8*>(
        &Qb[(size_t)(q0 + l15)*HD_ + ks*32 + (lhi<<3)]);

  f32x4 O[8];
  f32x4 zero4 = {0.f,0.f,0.f,0.f};
  #pragma unroll
  for (int of=0; of<8; of++) O[of] = zero4;
  float m_ = -__builtin_inff();
  float l_ = 0.f;
  const float scale = 0.08838834764831845f;  // 1/sqrt(128)

  const int addrA = (l15 + ((lhi & 1) << 5)) << 2;  // src lane lambda_a = 2*(lhi&1)
  const int addrB = addrA + 64;                     // lambda_b = lambda_a + 1
  const bool hi = (lhi >> 1) != 0;

  for (int kt = w; kt < KT; kt += 4) {
    const u16* Kt = Kb + (size_t)kt*64*HD_;
    // S^T = mfma(K, Q): s[n][r] -> key = kt*64 + 16n + 4*lhi + r, q = q0 + l15
    f32x4 s[4];
    #pragma unroll
    for (int n=0;n<4;n++) s[n] = zero4;
    __builtin_amdgcn_s_setprio(1);
    #pragma unroll
    for (int ks=0;ks<4;ks++)
      #pragma unroll
      for (int n=0;n<4;n++){
        short8 kbf = *reinterpret_cast<const short8*>(
            &Kt[(size_t)(n*16 + l15)*HD_ + ks*32 + (lhi<<3)]);
        s[n] = __builtin_amdgcn_mfma_f32_16x16x32_bf16(kbf, qf[ks], s[n], 0, 0, 0);
      }
    __builtin_amdgcn_s_setprio(0);

    // scale (+ causal mask on diagonal tile only)
    if (kt == KT-1) {
      #pragma unroll
      for (int n=0;n<4;n++){
        #pragma unroll
        for (int r=0;r<4;r++){
          int key = kt*64 + n*16 + (lhi<<2) + r;
          s[n][r] = (key <= q0 + l15) ? s[n][r]*scale : -__builtin_inff();
        }
      }
    } else {
      #pragma unroll
      for (int n=0;n<4;n++)
        #pragma unroll
        for (int r=0;r<4;r++) s[n][r] *= scale;
    }

    // row stats for q = l15: in-reg tree + 2 shfl stages
    float mx = s[0][0];
    #pragma unroll
    for (int n=0;n<4;n++)
      #pragma unroll
      for (int r=0;r<4;r++) mx = fmaxf(mx, s[n][r]);
    mx = fmaxf(mx, __shfl_xor(mx, 16, 64));
    mx = fmaxf(mx, __shfl_xor(mx, 32, 64));
    float mnew = fmaxf(m_, mx);
    float alpha = __expf(m_ - mnew);
    m_ = mnew;
    float rsum = 0.f;
    #pragma unroll
    for (int n=0;n<4;n++)
      #pragma unroll
      for (int r=0;r<4;r++){
        float p = __expf(s[n][r] - mnew);
        s[n][r] = p;
        rsum += p;
      }
    rsum += __shfl_xor(rsum, 16, 64);
    rsum += __shfl_xor(rsum, 32, 64);
    l_ = l_*alpha + rsum;

    // pack P to bf16 pairs (per n: regs {0,1} and {2,3})
    unsigned pk0[4], pk1[4];
    #pragma unroll
    for (int n=0;n<4;n++){
      pk0[n] = cvtpk_bf16(s[n][0], s[n][1]);
      pk1[n] = cvtpk_bf16(s[n][2], s[n][3]);
    }

    // rescale O rows (row = 4*lhi + r; alpha lives in lane (4*lhi + r))
    float arow[4];
    #pragma unroll
    for (int r=0;r<4;r++) arow[r] = __shfl(alpha, (lhi<<2) + r, 64);
    #pragma unroll
    for (int of=0; of<8; of++)
      #pragma unroll
      for (int r=0;r<4;r++) O[of][r] *= arow[r];

    // build PV A-frags: pa[ks2][j] = P[q=l15][key=32*ks2+8*lhi+j]
    short8 pa[2];
    #pragma unroll
    for (int ks2=0; ks2<2; ks2++){
      unsigned a0 = __builtin_amdgcn_ds_bpermute(addrA, (int)pk0[2*ks2]);
      unsigned b0 = __builtin_amdgcn_ds_bpermute(addrA, (int)pk0[2*ks2+1]);
      unsigned a1 = __builtin_amdgcn_ds_bpermute(addrA, (int)pk1[2*ks2]);
      unsigned b1 = __builtin_amdgcn_ds_bpermute(addrA, (int)pk1[2*ks2+1]);
      unsigned a2 = __builtin_amdgcn_ds_bpermute(addrB, (int)pk0[2*ks2]);
      unsigned b2 = __builtin_amdgcn_ds_bpermute(addrB, (int)pk0[2*ks2+1]);
      unsigned a3 = __builtin_amdgcn_ds_bpermute(addrB, (int)pk1[2*ks2]);
      unsigned b3 = __builtin_amdgcn_ds_bpermute(addrB, (int)pk1[2*ks2+1]);
      union { u32x4 u; short8 s8; } t;
      t.u[0] = hi ? b0 : a0;
      t.u[1] = hi ? b1 : a1;
      t.u[2] = hi ? b2 : a2;
      t.u[3] = hi ? b3 : a3;
      pa[ks2] = t.s8;
    }

    // PV: O[of] (row = q = 4*lhi + r, col d = 16*of + l15)
    const u16* Vk = Vtb + (size_t)kt*64 + (lhi<<3);
    __builtin_amdgcn_s_setprio(1);
    #pragma unroll
    for (int ks2=0; ks2<2; ks2++){
      #pragma unroll
      for (int of=0; of<8; of++){
        short8 vbf = *reinterpret_cast<const short8*>(
            Vk + ks2*32 + (size_t)(of*16 + l15)*L_);
        O[of] = __builtin_amdgcn_mfma_f32_16x16x32_bf16(pa[ks2], vbf, O[of], 0, 0, 0);
      }
    }
    __builtin_amdgcn_s_setprio(0);
  }

  // publish partials (m_, l_ valid per q = l15 in every lane)
  if (lane < 16) { Ml[w][l15] = m_; Ll[w][l15] = l_; }
  #pragma unroll
  for (int of=0; of<8; of++)
    #pragma unroll
    for (int r=0;r<4;r++)
      Ol[w][(lhi<<2)+r][of*16 + l15] = O[of][r];
  __syncthreads();

  // merge 4 key-split partials; thread -> (row, 8 cols)
  {
    int row = tid >> 4;
    int d0  = (tid & 15) * 8;
    float mw[4], lw[4];
    float M = -__builtin_inff();
    #pragma unroll
    for (int w2=0; w2<4; w2++){ mw[w2]=Ml[w2][row]; lw[w2]=Ll[w2][row]; M = fmaxf(M, mw[w2]); }
    float den = 0.f, cw[4];
    #pragma unroll
    for (int w2=0; w2<4; w2++){ float e = __expf(mw[w2]-M); cw[w2]=e; den += lw[w2]*e; }
    float inv = 1.0f/den;
    f32x4 o0 = zero4, o1 = zero4;
    #pragma unroll
    for (int w2=0; w2<4; w2++){
      f32x4 p0 = *reinterpret_cast<const f32x4*>(&Ol[w2][row][d0]);
      f32x4 p1 = *reinterpret_cast<const f32x4*>(&Ol[w2][row][d0+4]);
      #pragma unroll
      for (int j=0;j<4;j++){ o0[j] += cw[w2]*p0[j]; o1[j] += cw[w2]*p1[j]; }
    }
    short8 st;
    #pragma unroll
    for (int j=0;j<4;j++){ st[j] = (short)f2bf(o0[j]*inv); st[j+4] = (short)f2bf(o1[j]*inv); }
    *reinterpret_cast<short8*>(&AO[((size_t)b*L_ + q0 + row)*HD_ + d0]) = st;
  }
}

// ---------------- output projection ----------------
__global__ __launch_bounds__(256) void proj_kernel(
    const u16* __restrict__ AO, const u16* __restrict__ Wt_o,
    const float* __restrict__ bo, float* __restrict__ out)
{
  const int nb = blockIdx.x;   // 0..15
  const int rb = blockIdx.y;   // 0..127
  const int tid = threadIdx.x, lane = tid & 63, w = tid >> 6;
  const int wr = w >> 1, wc = w & 1;
  const int l15 = lane & 15, lhi = lane >> 4;
  const int row0 = rb * 128, n0 = nb * 128;

  __shared__ u16 Al[128][136];
  __shared__ u16 Bl[128][136];

  #pragma unroll
  for (int i=0;i<8;i++){
    int chunk = i*256 + tid;
    int r = chunk >> 4;
    int c = (chunk & 15) * 8;
    *reinterpret_cast<short8*>(&Al[r][c]) =
        *reinterpret_cast<const short8*>(&AO[(size_t)(row0+r)*HD_ + c]);
    *reinterpret_cast<short8*>(&Bl[r][c]) =
        *reinterpret_cast<const short8*>(&Wt_o[(size_t)(n0+r)*HD_ + c]);
  }
  __syncthreads();

  f32x4 acc[4][4];
  f32x4 zero4 = {0.f,0.f,0.f,0.f};
  for (int m=0;m<4;m++) for (int n=0;n<4;n++) acc[m][n] = zero4;

  #pragma unroll
  for (int ks=0; ks<128; ks+=32){
    short8 fa[4], fb[4];
    #pragma unroll
    for (int m=0;m<4;m++)
      fa[m] = *reinterpret_cast<const short8*>(&Al[wr*64 + m*16 + l15][ks + (lhi<<3)]);
    #pragma unroll
    for (int n=0;n<4;n++)
      fb[n] = *reinterpret_cast<const short8*>(&Bl[wc*64 + n*16 + l15][ks + (lhi<<3)]);
    #pragma unroll
    for (int m=0;m<4;m++)
      #pragma unroll
      for (int n=0;n<4;n++)
        acc[m][n] = __builtin_amdgcn_mfma_f32_16x16x32_bf16(fa[m], fb[n], acc[m][n], 0, 0, 0);
  }

  #pragma unroll
  for (int n=0;n<4;n++){
    int col = n0 + wc*64 + n*16 + l15;
    float b = bo[col];
    #pragma unroll
    for (int m=0;m<4;m++){
      #pragma unroll
      for (int r=0;r<4;r++){
        int row = row0 + wr*64 + m*16 + (lhi<<2) + r;
        out[(size_t)row*D_ + col] = acc[m][n][r] + b;
      }
    }
  }
}

// ---------------- launch ----------------
extern "C" void kernel_launch(void* const* d_in, const int* in_sizes, int n_in,
                              void* d_out, int out_size, void* d_ws, size_t ws_size,
                              hipStream_t stream) {
  const float* x  = (const float*)d_in[0];
  const float* Wq = (const float*)d_in[1];
  const float* bq = (const float*)d_in[2];
  const float* Wk = (const float*)d_in[3];
  const float* bk = (const float*)d_in[4];
  const float* Wv = (const float*)d_in[5];
  const float* bv = (const float*)d_in[6];
  const float* Wo = (const float*)d_in[7];
  const float* bo = (const float*)d_in[8];
  float* out = (float*)d_out;

  u16* ws      = (u16*)d_ws;
  u16* Wt_qkv  = ws;                            // [384][2048]
  u16* Wt_o    = Wt_qkv + 3*HD_*D_;             // [2048][128]
  u16* Q       = Wt_o   + (size_t)D_*HD_;       // [B*L][128]
  u16* K       = Q + (size_t)M_*HD_;            // [B*L][128]
  u16* Vt      = K + (size_t)M_*HD_;            // [B][128][4096]
  u16* AO      = Vt + (size_t)M_*HD_;           // [B*L][128]

  prep_kernel<<<256, 256, 0, stream>>>(Wq, Wk, Wv, Wo, Wt_qkv, Wt_o);
  qkv_kernel<<<256, 512, 0, stream>>>(x, Wt_qkv, bq, bk, bv, Q, K, Vt);
  attn_kernel<<<1024, 256, 0, stream>>>(Q, K, Vt, AO);
  proj_kernel<<<dim3(16, 128), 256, 0, stream>>>(AO, Wt_o, bo, out);
}

// Round 6
// 190.545 us; speedup vs baseline: 1.2814x; 1.2814x over previous
//
#include <hip/hip_runtime.h>

#define B_  4
#define L_  4096
#define D_  2048
#define HD_ 128
#define M_  (B_*L_)   // 16384

typedef __attribute__((ext_vector_type(8))) short short8;
typedef __attribute__((ext_vector_type(4))) float f32x4;
typedef __attribute__((ext_vector_type(16))) float f32x16;
typedef __attribute__((ext_vector_type(4))) unsigned short u16x4;
typedef __attribute__((ext_vector_type(4))) unsigned int u32x4;
typedef unsigned short u16;

#define GLL16(g, l) __builtin_amdgcn_global_load_lds( \
    (const __attribute__((address_space(1))) void*)(g), \
    (__attribute__((address_space(3))) void*)(l), 16, 0, 0)

__device__ __forceinline__ u16 f2bf(float f){
  union { float f; unsigned u; } v; v.f = f;
  unsigned r = v.u + 0x7FFFu + ((v.u >> 16) & 1u);
  return (u16)(r >> 16);
}

__device__ __forceinline__ unsigned cvtpk_bf16(float a, float b){
  unsigned r;
  asm volatile("v_cvt_pk_bf16_f32 %0, %1, %2" : "=v"(r) : "v"(a), "v"(b));
  return r;
}

// ---------------- prep: weight transposes to bf16 (weights only) ----------
__global__ __launch_bounds__(256) void prep_kernel(
    const float* __restrict__ Wq, const float* __restrict__ Wk,
    const float* __restrict__ Wv, const float* __restrict__ Wo,
    u16* __restrict__ Wt_qkv, u16* __restrict__ Wt_o)
{
  __shared__ float T[64][68];
  const int tid = threadIdx.x;
  int tb = blockIdx.x;                 // 0..255
  int mat = tb >> 6, t = tb & 63;
  const float* src; u16* dst; int Rw, Cw, rt, ct;
  if (mat < 3) {
    src = (mat==0) ? Wq : (mat==1) ? Wk : Wv;
    dst = Wt_qkv + (size_t)mat*HD_*D_;
    Rw = D_; Cw = HD_; rt = t >> 1; ct = t & 1;
  } else {
    src = Wo; dst = Wt_o;
    Rw = HD_; Cw = D_; rt = t >> 5; ct = t & 31;
  }
  int r0 = rt*64, c0 = ct*64;
  #pragma unroll
  for (int i=0;i<4;i++){
    int fid = i*256 + tid;
    int row = fid >> 4, c4 = (fid & 15) * 4;
    float4 v = *reinterpret_cast<const float4*>(src + (size_t)(r0+row)*Cw + c0 + c4);
    *reinterpret_cast<float4*>(&T[row][c4]) = v;
  }
  __syncthreads();
  #pragma unroll
  for (int i=0;i<2;i++){
    int sid = i*256 + tid;
    int crow = sid >> 3, k8 = (sid & 7) * 8;
    short8 o;
    #pragma unroll
    for (int j=0;j<8;j++) o[j] = (short)f2bf(T[k8+j][crow]);
    *reinterpret_cast<short8*>(dst + (size_t)(c0+crow)*Rw + r0 + k8) = o;
  }
}

// ---------------- fused QKV GEMM (x cast fused, x read ONCE) ---------------
// Softmax scale is folded into Q here (Q := (xWq+bq)/sqrt(HD)).
__global__ __launch_bounds__(512, 2) void qkv_kernel(
    const float* __restrict__ x, const u16* __restrict__ Wt,
    const float* __restrict__ bq, const float* __restrict__ bk,
    const float* __restrict__ bv,
    u16* __restrict__ Q, u16* __restrict__ K, u16* __restrict__ Vt)
{
  const int rb = blockIdx.x;          // 0..255
  const int tid  = threadIdx.x;
  const int lane = tid & 63, w = tid >> 6;
  const int wr = w >> 2, wc = w & 3;
  const int l15 = lane & 15, lhi = lane >> 4;
  const int row0 = rb * 64;

  __shared__ u16 Asm[64*64];          // x tile bf16, swizzled
  __shared__ u16 Bsm[384*64];         // Wqkv^T tile, swizzled

  const u16* bSrc[6]; u16* bDst[6];
  #pragma unroll
  for (int i=0;i<6;i++){
    int id = i*512 + w*64 + lane;
    int r = id >> 3, c = (id & 7) * 8;
    bSrc[i] = Wt + (size_t)r*D_ + (c ^ ((r&7)*8));
    bDst[i] = Bsm + i*4096 + w*512;
  }
  const int ar = tid >> 3, ac = (tid & 7) * 8;
  const int aoff = ar*64 + (ac ^ ((ar&7)*8));
  const float* xrow = x + (size_t)(row0+ar)*D_ + ac;

  int offA[2][2], offB[2][6];
  #pragma unroll
  for (int ks=0;ks<2;ks++){
    #pragma unroll
    for (int m=0;m<2;m++){
      int rA = wr*32 + m*16 + l15;
      offA[ks][m] = rA*64 + ((ks*32 + lhi*8) ^ ((rA&7)*8));
    }
    #pragma unroll
    for (int n=0;n<6;n++){
      int rB = wc*96 + n*16 + l15;
      offB[ks][n] = rB*64 + ((ks*32 + lhi*8) ^ ((rB&7)*8));
    }
  }

  f32x4 acc[2][6];
  f32x4 zero4 = {0.f,0.f,0.f,0.f};
  #pragma unroll
  for (int m=0;m<2;m++)
    #pragma unroll
    for (int n=0;n<6;n++) acc[m][n] = zero4;

  float4 f0 = *reinterpret_cast<const float4*>(xrow);
  float4 f1 = *reinterpret_cast<const float4*>(xrow + 4);

  for (int k0 = 0; k0 < D_; k0 += 64) {
    __syncthreads();
    {
      short8 a8;
      a8[0]=(short)f2bf(f0.x); a8[1]=(short)f2bf(f0.y);
      a8[2]=(short)f2bf(f0.z); a8[3]=(short)f2bf(f0.w);
      a8[4]=(short)f2bf(f1.x); a8[5]=(short)f2bf(f1.y);
      a8[6]=(short)f2bf(f1.z); a8[7]=(short)f2bf(f1.w);
      *reinterpret_cast<short8*>(Asm + aoff) = a8;
    }
    #pragma unroll
    for (int i=0;i<6;i++){ GLL16(bSrc[i], bDst[i]); bSrc[i] += 64; }
    __syncthreads();
    if (k0 + 64 < D_) {
      const float* xp = xrow + k0 + 64;
      f0 = *reinterpret_cast<const float4*>(xp);
      f1 = *reinterpret_cast<const float4*>(xp + 4);
    }
    #pragma unroll
    for (int ks=0;ks<2;ks++){
      short8 fa[2], fb[6];
      #pragma unroll
      for (int m=0;m<2;m++) fa[m] = *reinterpret_cast<const short8*>(Asm + offA[ks][m]);
      #pragma unroll
      for (int n=0;n<6;n++) fb[n] = *reinterpret_cast<const short8*>(Bsm + offB[ks][n]);
      #pragma unroll
      for (int m=0;m<2;m++)
        #pragma unroll
        for (int n=0;n<6;n++)
          acc[m][n] = __builtin_amdgcn_mfma_f32_16x16x32_bf16(fa[m], fb[n], acc[m][n], 0, 0, 0);
    }
  }

  const float qscale = 0.08838834764831845f;  // 1/sqrt(128)
  #pragma unroll
  for (int n=0;n<6;n++){
    int col = wc*96 + n*16 + l15;
    int j = col >> 7;            // 0:Q 1:K 2:V
    int c = col & 127;
    float bi = (j==0) ? bq[c] : (j==1) ? bk[c] : bv[c];
    #pragma unroll
    for (int m=0;m<2;m++){
      int rowb = row0 + wr*32 + m*16 + (lhi<<2);
      if (j == 0) {
        #pragma unroll
        for (int r=0;r<4;r++)
          Q[(size_t)(rowb+r)*HD_ + c] = f2bf((acc[m][n][r] + bi) * qscale);
      } else if (j == 1) {
        #pragma unroll
        for (int r=0;r<4;r++)
          K[(size_t)(rowb+r)*HD_ + c] = f2bf(acc[m][n][r] + bi);
      } else {
        int bb = rowb >> 12;
        int l  = rowb & (L_-1);
        u16x4 v4;
        #pragma unroll
        for (int r=0;r<4;r++) v4[r] = f2bf(acc[m][n][r] + bi);
        *reinterpret_cast<u16x4*>(Vt + (size_t)bb*HD_*L_ + (size_t)c*L_ + l) = v4;
      }
    }
  }
}

// ---------------- flash attention: 32x32 swapped-QK^T, in-reg softmax ------
// grid 512 (2 blocks/CU): block = 32 q-rows; 4 waves key-split (kt = w mod 4).
// S^T = mfma_32x32x16(K,Q): lane owns q = lane&31 (32 S-vals), 1 shfl stage.
// P^T built in-reg (cvt_pk + shfl_xor(32) + cndmask). O^T = mfma(Vt, P^T).
// Defer-max (THR=8) skips O-rescale. Merge 4 key-split partials via LDS.
__global__ __launch_bounds__(256, 2) void attn_kernel(
    const u16* __restrict__ Qg, const u16* __restrict__ Kg,
    const u16* __restrict__ Vtg, u16* __restrict__ AO)
{
  const int blk = blockIdx.x;
  const int xcd = blk & 7;
  const int sub = blk >> 3;                    // 0..63
  const int b   = xcd >> 1;                    // batch -> XCD pair
  const int strip = 127 - (2*sub + (xcd & 1)); // long strips dispatch first
  const int q0  = strip * 32;
  const int KT  = (strip >> 1) + 1;            // #64-key tiles

  const int tid = threadIdx.x, lane = tid & 63, w = tid >> 6;
  const int l31 = lane & 31;
  const int hi  = lane >> 5;

  const u16* Qb  = Qg  + (size_t)b * L_ * HD_;
  const u16* Kb  = Kg  + (size_t)b * L_ * HD_;
  const u16* Vtb = Vtg + (size_t)b * HD_ * L_;

  __shared__ __attribute__((aligned(16))) float Ol[4][32][132];
  __shared__ float Ml[4][32], Ll[4][32];

  // Q B-frags: qf[ks] = Q[q0+l31][ks*16 + 8hi .. +8]
  short8 qf[8];
  #pragma unroll
  for (int ks=0; ks<8; ks++)
    qf[ks] = *reinterpret_cast<const short8*>(
        &Qb[(size_t)(q0 + l31)*HD_ + ks*16 + hi*8]);

  f32x16 O[4];
  #pragma unroll
  for (int nb=0; nb<4; nb++)
    #pragma unroll
    for (int i=0;i<16;i++) O[nb][i] = 0.f;
  float m_ = -__builtin_inff();
  float l_ = 0.f;

  for (int kt = w; kt < KT; kt += 4) {
    const u16* Kt = Kb + (size_t)kt*64*HD_;
    // S^T[key][q]: key = kt*64 + 32n + (reg&3)+8*(reg>>2)+4*hi, q = q0+l31
    f32x16 s[2];
    #pragma unroll
    for (int n=0;n<2;n++)
      #pragma unroll
      for (int i=0;i<16;i++) s[n][i] = 0.f;
    __builtin_amdgcn_s_setprio(1);
    #pragma unroll
    for (int ks=0;ks<8;ks++)
      #pragma unroll
      for (int n=0;n<2;n++){
        short8 ka = *reinterpret_cast<const short8*>(
            &Kt[(size_t)(n*32 + l31)*HD_ + ks*16 + hi*8]);
        s[n] = __builtin_amdgcn_mfma_f32_32x32x16_bf16(ka, qf[ks], s[n], 0, 0, 0);
      }
    __builtin_amdgcn_s_setprio(0);

    // causal mask (diagonal tile only; scale already folded into Q)
    if (kt == KT-1) {
      #pragma unroll
      for (int n=0;n<2;n++)
        #pragma unroll
        for (int reg=0;reg<16;reg++){
          int key = kt*64 + n*32 + (reg&3) + 8*(reg>>2) + 4*hi;
          if (key > q0 + l31) s[n][reg] = -__builtin_inff();
        }
    }

    // row stats for q = l31 (32 vals in-reg + 1 shfl stage)
    float pmax = s[0][0];
    #pragma unroll
    for (int n=0;n<2;n++)
      #pragma unroll
      for (int reg=0;reg<16;reg++) pmax = fmaxf(pmax, s[n][reg]);
    pmax = fmaxf(pmax, __shfl_xor(pmax, 32, 64));

    // defer-max: skip rescale when growth <= 8
    if (!__all(pmax <= m_ + 8.f)) {
      float mnew = fmaxf(m_, pmax);
      float alpha = __expf(m_ - mnew);
      m_ = mnew;
      l_ *= alpha;
      #pragma unroll
      for (int nb=0; nb<4; nb++)
        #pragma unroll
        for (int i=0;i<16;i++) O[nb][i] *= alpha;
    }

    float rsum = 0.f;
    #pragma unroll
    for (int n=0;n<2;n++)
      #pragma unroll
      for (int reg=0;reg<16;reg++){
        float p = __expf(s[n][reg] - m_);
        s[n][reg] = p;
        rsum += p;
      }
    rsum += __shfl_xor(rsum, 32, 64);
    l_ += rsum;

    // pack P to bf16 pairs: c[n][i] = (P[.,2i], P[.,2i+1]) within frag order
    unsigned c[2][8], ox[2][8];
    #pragma unroll
    for (int n=0;n<2;n++)
      #pragma unroll
      for (int i=0;i<8;i++)
        c[n][i] = cvtpk_bf16(s[n][2*i], s[n][2*i+1]);
    #pragma unroll
    for (int n=0;n<2;n++)
      #pragma unroll
      for (int i=0;i<8;i++)
        ox[n][i] = (unsigned)__shfl_xor((int)c[n][i], 32, 64);

    // build P^T B-frags: pb[ks] holds P[q=l31][16ks + 8hi + 0..7]
    short8 pb[4];
    #pragma unroll
    for (int n=0;n<2;n++)
      #pragma unroll
      for (int sB=0;sB<2;sB++){
        union { u32x4 u; short8 s8; } t;
        t.u[0] = hi ? ox[n][4*sB+2] : c[n][4*sB+0];
        t.u[1] = hi ? ox[n][4*sB+3] : c[n][4*sB+1];
        t.u[2] = hi ? c[n][4*sB+2]  : ox[n][4*sB+0];
        t.u[3] = hi ? c[n][4*sB+3]  : ox[n][4*sB+1];
        pb[2*n+sB] = t.s8;
      }

    // PV: O^T[d][q] += V^T[d][k] P^T[k][q]
    const u16* Vk = Vtb + (size_t)kt*64 + hi*8;
    __builtin_amdgcn_s_setprio(1);
    #pragma unroll
    for (int ks=0; ks<4; ks++){
      #pragma unroll
      for (int nb=0; nb<4; nb++){
        short8 av = *reinterpret_cast<const short8*>(
            Vk + (size_t)(nb*32 + l31)*L_ + ks*16);
        O[nb] = __builtin_amdgcn_mfma_f32_32x32x16_bf16(av, pb[ks], O[nb], 0, 0, 0);
      }
    }
    __builtin_amdgcn_s_setprio(0);
  }

  // publish partials
  if (hi == 0) { Ml[w][l31] = m_; Ll[w][l31] = l_; }
  #pragma unroll
  for (int nb=0; nb<4; nb++)
    #pragma unroll
    for (int g=0; g<4; g++){
      f32x4 v;
      v[0]=O[nb][4*g+0]; v[1]=O[nb][4*g+1]; v[2]=O[nb][4*g+2]; v[3]=O[nb][4*g+3];
      *reinterpret_cast<f32x4*>(&Ol[w][l31][nb*32 + g*8 + hi*4]) = v;
    }
  __syncthreads();

  // merge 4 key-split partials; thread -> (q, 16 d)
  {
    int q  = tid >> 3;
    int dc = (tid & 7) * 16;
    float mw[4], lw[4];
    float M = -__builtin_inff();
    #pragma unroll
    for (int w2=0; w2<4; w2++){ mw[w2]=Ml[w2][q]; lw[w2]=Ll[w2][q]; M = fmaxf(M, mw[w2]); }
    float den = 0.f, cw[4];
    #pragma unroll
    for (int w2=0; w2<4; w2++){ float e = __expf(mw[w2]-M); cw[w2]=e; den += lw[w2]*e; }
    float inv = 1.0f/den;
    float o[16];
    #pragma unroll
    for (int j=0;j<16;j++) o[j] = 0.f;
    #pragma unroll
    for (int w2=0; w2<4; w2++){
      #pragma unroll
      for (int g=0; g<4; g++){
        f32x4 p = *reinterpret_cast<const f32x4*>(&Ol[w2][q][dc + g*4]);
        #pragma unroll
        for (int j=0;j<4;j++) o[g*4+j] += cw[w2]*p[j];
      }
    }
    short8 st0, st1;
    #pragma unroll
    for (int j=0;j<8;j++){ st0[j] = (short)f2bf(o[j]*inv); st1[j] = (short)f2bf(o[8+j]*inv); }
    u16* dst = &AO[((size_t)b*L_ + q0 + q)*HD_ + dc];
    *reinterpret_cast<short8*>(dst)     = st0;
    *reinterpret_cast<short8*>(dst + 8) = st1;
  }
}

// ---------------- output projection ----------------
__global__ __launch_bounds__(256) void proj_kernel(
    const u16* __restrict__ AO, const u16* __restrict__ Wt_o,
    const float* __restrict__ bo, float* __restrict__ out)
{
  const int nb = blockIdx.x;   // 0..15
  const int rb = blockIdx.y;   // 0..127
  const int tid = threadIdx.x, lane = tid & 63, w = tid >> 6;
  const int wr = w >> 1, wc = w & 1;
  const int l15 = lane & 15, lhi = lane >> 4;
  const int row0 = rb * 128, n0 = nb * 128;

  __shared__ u16 Al[128][136];
  __shared__ u16 Bl[128][136];

  #pragma unroll
  for (int i=0;i<8;i++){
    int chunk = i*256 + tid;
    int r = chunk >> 4;
    int c = (chunk & 15) * 8;
    *reinterpret_cast<short8*>(&Al[r][c]) =
        *reinterpret_cast<const short8*>(&AO[(size_t)(row0+r)*HD_ + c]);
    *reinterpret_cast<short8*>(&Bl[r][c]) =
        *reinterpret_cast<const short8*>(&Wt_o[(size_t)(n0+r)*HD_ + c]);
  }
  __syncthreads();

  f32x4 acc[4][4];
  f32x4 zero4 = {0.f,0.f,0.f,0.f};
  for (int m=0;m<4;m++) for (int n=0;n<4;n++) acc[m][n] = zero4;

  #pragma unroll
  for (int ks=0; ks<128; ks+=32){
    short8 fa[4], fb[4];
    #pragma unroll
    for (int m=0;m<4;m++)
      fa[m] = *reinterpret_cast<const short8*>(&Al[wr*64 + m*16 + l15][ks + (lhi<<3)]);
    #pragma unroll
    for (int n=0;n<4;n++)
      fb[n] = *reinterpret_cast<const short8*>(&Bl[wc*64 + n*16 + l15][ks + (lhi<<3)]);
    #pragma unroll
    for (int m=0;m<4;m++)
      #pragma unroll
      for (int n=0;n<4;n++)
        acc[m][n] = __builtin_amdgcn_mfma_f32_16x16x32_bf16(fa[m], fb[n], acc[m][n], 0, 0, 0);
  }

  #pragma unroll
  for (int n=0;n<4;n++){
    int col = n0 + wc*64 + n*16 + l15;
    float b = bo[col];
    #pragma unroll
    for (int m=0;m<4;m++){
      #pragma unroll
      for (int r=0;r<4;r++){
        int row = row0 + wr*64 + m*16 + (lhi<<2) + r;
        out[(size_t)row*D_ + col] = acc[m][n][r] + b;
      }
    }
  }
}

// ---------------- launch ----------------
extern "C" void kernel_launch(void* const* d_in, const int* in_sizes, int n_in,
                              void* d_out, int out_size, void* d_ws, size_t ws_size,
                              hipStream_t stream) {
  const float* x  = (const float*)d_in[0];
  const float* Wq = (const float*)d_in[1];
  const float* bq = (const float*)d_in[2];
  const float* Wk = (const float*)d_in[3];
  const float* bk = (const float*)d_in[4];
  const float* Wv = (const float*)d_in[5];
  const float* bv = (const float*)d_in[6];
  const float* Wo = (const float*)d_in[7];
  const float* bo = (const float*)d_in[8];
  float* out = (float*)d_out;

  u16* ws      = (u16*)d_ws;
  u16* Wt_qkv  = ws;                            // [384][2048]
  u16* Wt_o    = Wt_qkv + 3*HD_*D_;             // [2048][128]
  u16* Q       = Wt_o   + (size_t)D_*HD_;       // [B*L][128] (pre-scaled)
  u16* K       = Q + (size_t)M_*HD_;            // [B*L][128]
  u16* Vt      = K + (size_t)M_*HD_;            // [B][128][4096]
  u16* AO      = Vt + (size_t)M_*HD_;           // [B*L][128]

  prep_kernel<<<256, 256, 0, stream>>>(Wq, Wk, Wv, Wo, Wt_qkv, Wt_o);
  qkv_kernel<<<256, 512, 0, stream>>>(x, Wt_qkv, bq, bk, bv, Q, K, Vt);
  attn_kernel<<<512, 256, 0, stream>>>(Q, K, Vt, AO);
  proj_kernel<<<dim3(16, 128), 256, 0, stream>>>(AO, Wt_o, bo, out);
}

// Round 7
// 169.103 us; speedup vs baseline: 1.4438x; 1.1268x over previous
//
#include <hip/hip_runtime.h>

#define B_  4
#define L_  4096
#define D_  2048
#define HD_ 128
#define M_  (B_*L_)   // 16384

typedef __attribute__((ext_vector_type(8))) short short8;
typedef __attribute__((ext_vector_type(4))) float f32x4;
typedef __attribute__((ext_vector_type(16))) float f32x16;
typedef __attribute__((ext_vector_type(4))) unsigned short u16x4;
typedef __attribute__((ext_vector_type(4))) unsigned int u32x4;
typedef unsigned short u16;

#define GLL16(g, l) __builtin_amdgcn_global_load_lds( \
    (const __attribute__((address_space(1))) void*)(g), \
    (__attribute__((address_space(3))) void*)(l), 16, 0, 0)

__device__ __forceinline__ u16 f2bf(float f){
  union { float f; unsigned u; } v; v.f = f;
  unsigned r = v.u + 0x7FFFu + ((v.u >> 16) & 1u);
  return (u16)(r >> 16);
}

__device__ __forceinline__ unsigned cvtpk_bf16(float a, float b){
  unsigned r;
  asm volatile("v_cvt_pk_bf16_f32 %0, %1, %2" : "=v"(r) : "v"(a), "v"(b));
  return r;
}

// ---------------- prep: weight transposes to bf16 (weights only) ----------
__global__ __launch_bounds__(256) void prep_kernel(
    const float* __restrict__ Wq, const float* __restrict__ Wk,
    const float* __restrict__ Wv, const float* __restrict__ Wo,
    u16* __restrict__ Wt_qkv, u16* __restrict__ Wt_o)
{
  __shared__ float T[64][68];
  const int tid = threadIdx.x;
  int tb = blockIdx.x;                 // 0..255
  int mat = tb >> 6, t = tb & 63;
  const float* src; u16* dst; int Rw, Cw, rt, ct;
  if (mat < 3) {
    src = (mat==0) ? Wq : (mat==1) ? Wk : Wv;
    dst = Wt_qkv + (size_t)mat*HD_*D_;
    Rw = D_; Cw = HD_; rt = t >> 1; ct = t & 1;
  } else {
    src = Wo; dst = Wt_o;
    Rw = HD_; Cw = D_; rt = t >> 5; ct = t & 31;
  }
  int r0 = rt*64, c0 = ct*64;
  #pragma unroll
  for (int i=0;i<4;i++){
    int fid = i*256 + tid;
    int row = fid >> 4, c4 = (fid & 15) * 4;
    float4 v = *reinterpret_cast<const float4*>(src + (size_t)(r0+row)*Cw + c0 + c4);
    *reinterpret_cast<float4*>(&T[row][c4]) = v;
  }
  __syncthreads();
  #pragma unroll
  for (int i=0;i<2;i++){
    int sid = i*256 + tid;
    int crow = sid >> 3, k8 = (sid & 7) * 8;
    short8 o;
    #pragma unroll
    for (int j=0;j<8;j++) o[j] = (short)f2bf(T[k8+j][crow]);
    *reinterpret_cast<short8*>(dst + (size_t)(c0+crow)*Rw + r0 + k8) = o;
  }
}

// ---------------- fused QKV GEMM (x cast fused, x read ONCE) ---------------
// Q pre-scaled by 1/sqrt(HD). K/V written in attn fragment-major layouts:
//   Kf[b][kt][n][ks][lane][8]: lane=hi*32+l31 holds K[key=n*32+l31][d=ks*16+hi*8..+8]
//   Vf[b][kt][ks][nb][lane][8]: lane=hi*32+l31 holds V^T[d=nb*32+l31][k=ks*16+hi*8..+8]
__global__ __launch_bounds__(512, 2) void qkv_kernel(
    const float* __restrict__ x, const u16* __restrict__ Wt,
    const float* __restrict__ bq, const float* __restrict__ bk,
    const float* __restrict__ bv,
    u16* __restrict__ Q, u16* __restrict__ Kf, u16* __restrict__ Vf)
{
  const int rb = blockIdx.x;          // 0..255
  const int tid  = threadIdx.x;
  const int lane = tid & 63, w = tid >> 6;
  const int wr = w >> 2, wc = w & 3;
  const int l15 = lane & 15, lhi = lane >> 4;
  const int row0 = rb * 64;

  __shared__ u16 Asm[64*64];          // x tile bf16, swizzled
  __shared__ u16 Bsm[384*64];         // Wqkv^T tile, swizzled

  const u16* bSrc[6]; u16* bDst[6];
  #pragma unroll
  for (int i=0;i<6;i++){
    int id = i*512 + w*64 + lane;
    int r = id >> 3, c = (id & 7) * 8;
    bSrc[i] = Wt + (size_t)r*D_ + (c ^ ((r&7)*8));
    bDst[i] = Bsm + i*4096 + w*512;
  }
  const int ar = tid >> 3, ac = (tid & 7) * 8;
  const int aoff = ar*64 + (ac ^ ((ar&7)*8));
  const float* xrow = x + (size_t)(row0+ar)*D_ + ac;

  int offA[2][2], offB[2][6];
  #pragma unroll
  for (int ks=0;ks<2;ks++){
    #pragma unroll
    for (int m=0;m<2;m++){
      int rA = wr*32 + m*16 + l15;
      offA[ks][m] = rA*64 + ((ks*32 + lhi*8) ^ ((rA&7)*8));
    }
    #pragma unroll
    for (int n=0;n<6;n++){
      int rB = wc*96 + n*16 + l15;
      offB[ks][n] = rB*64 + ((ks*32 + lhi*8) ^ ((rB&7)*8));
    }
  }

  f32x4 acc[2][6];
  f32x4 zero4 = {0.f,0.f,0.f,0.f};
  #pragma unroll
  for (int m=0;m<2;m++)
    #pragma unroll
    for (int n=0;n<6;n++) acc[m][n] = zero4;

  float4 f0 = *reinterpret_cast<const float4*>(xrow);
  float4 f1 = *reinterpret_cast<const float4*>(xrow + 4);

  for (int k0 = 0; k0 < D_; k0 += 64) {
    __syncthreads();
    {
      short8 a8;
      a8[0]=(short)f2bf(f0.x); a8[1]=(short)f2bf(f0.y);
      a8[2]=(short)f2bf(f0.z); a8[3]=(short)f2bf(f0.w);
      a8[4]=(short)f2bf(f1.x); a8[5]=(short)f2bf(f1.y);
      a8[6]=(short)f2bf(f1.z); a8[7]=(short)f2bf(f1.w);
      *reinterpret_cast<short8*>(Asm + aoff) = a8;
    }
    #pragma unroll
    for (int i=0;i<6;i++){ GLL16(bSrc[i], bDst[i]); bSrc[i] += 64; }
    __syncthreads();
    if (k0 + 64 < D_) {
      const float* xp = xrow + k0 + 64;
      f0 = *reinterpret_cast<const float4*>(xp);
      f1 = *reinterpret_cast<const float4*>(xp + 4);
    }
    #pragma unroll
    for (int ks=0;ks<2;ks++){
      short8 fa[2], fb[6];
      #pragma unroll
      for (int m=0;m<2;m++) fa[m] = *reinterpret_cast<const short8*>(Asm + offA[ks][m]);
      #pragma unroll
      for (int n=0;n<6;n++) fb[n] = *reinterpret_cast<const short8*>(Bsm + offB[ks][n]);
      #pragma unroll
      for (int m=0;m<2;m++)
        #pragma unroll
        for (int n=0;n<6;n++)
          acc[m][n] = __builtin_amdgcn_mfma_f32_16x16x32_bf16(fa[m], fb[n], acc[m][n], 0, 0, 0);
    }
  }

  const float qscale = 0.08838834764831845f;  // 1/sqrt(128)
  #pragma unroll
  for (int n=0;n<6;n++){
    int col = wc*96 + n*16 + l15;
    int j = col >> 7;            // 0:Q 1:K 2:V
    int c = col & 127;
    float bi = (j==0) ? bq[c] : (j==1) ? bk[c] : bv[c];
    #pragma unroll
    for (int m=0;m<2;m++){
      int rowb = row0 + wr*32 + m*16 + (lhi<<2);
      int bb = rowb >> 12;
      int l0 = rowb & (L_-1);
      if (j == 0) {
        #pragma unroll
        for (int r=0;r<4;r++)
          Q[(size_t)(rowb+r)*HD_ + c] = f2bf((acc[m][n][r] + bi) * qscale);
      } else if (j == 1) {
        // Kf: d=c fixed -> ks,hi,j fixed; key varies -> lane varies
        int ksd = c >> 4, hid = (c >> 3) & 1, jd = c & 7;
        #pragma unroll
        for (int r=0;r<4;r++){
          int l = l0 + r;
          int kt = l >> 6, k6 = l & 63;
          int n2 = k6 >> 5, l31k = k6 & 31;
          Kf[((size_t)bb*64 + kt)*8192 + (n2*8 + ksd)*512 + (hid*32 + l31k)*8 + jd]
              = f2bf(acc[m][n][r] + bi);
        }
      } else {
        // Vf: d=c fixed -> nb,l31 fixed; keys r=0..3 share one 8B chunk
        int nbv = (c >> 5) & 3, l31v = c & 31;
        int kt = l0 >> 6, k6 = l0 & 63;
        int ksv = k6 >> 4, hiv = (k6 >> 3) & 1, j0 = k6 & 7;
        u16x4 v4;
        #pragma unroll
        for (int r=0;r<4;r++) v4[r] = f2bf(acc[m][n][r] + bi);
        *reinterpret_cast<u16x4*>(
            Vf + ((size_t)bb*64 + kt)*8192 + (ksv*4 + nbv)*512 + (hiv*32 + l31v)*8 + j0) = v4;
      }
    }
  }
}

// ---------------- flash attention: 32x32 swapped-QK^T, frag-major K/V ------
// grid 512 (2/CU): block = 32 q-rows; 4 waves key-split (kt = w mod 4).
// All per-iter loads are lane-contiguous 1KB chunks (Kf/Vf layouts).
__global__ __launch_bounds__(256, 2) void attn_kernel(
    const u16* __restrict__ Qg, const u16* __restrict__ Kfg,
    const u16* __restrict__ Vfg, u16* __restrict__ AO)
{
  const int blk = blockIdx.x;
  const int xcd = blk & 7;
  const int sub = blk >> 3;                    // 0..63
  const int b   = xcd >> 1;                    // batch -> XCD pair
  const int strip = 127 - (2*sub + (xcd & 1)); // long strips dispatch first
  const int q0  = strip * 32;
  const int KT  = (strip >> 1) + 1;            // #64-key tiles

  const int tid = threadIdx.x, lane = tid & 63, w = tid >> 6;
  const int l31 = lane & 31;
  const int hi  = lane >> 5;

  const u16* Qb  = Qg  + (size_t)b * L_ * HD_;
  const u16* Kfb = Kfg + (size_t)b * 64 * 8192 + lane*8;
  const u16* Vfb = Vfg + (size_t)b * 64 * 8192 + lane*8;

  __shared__ __attribute__((aligned(16))) float Ol[4][32][132];
  __shared__ float Ml[4][32], Ll[4][32];

  // Q B-frags: qf[ks] = Q[q0+l31][ks*16 + 8hi .. +8] (Q pre-scaled)
  short8 qf[8];
  #pragma unroll
  for (int ks=0; ks<8; ks++)
    qf[ks] = *reinterpret_cast<const short8*>(
        &Qb[(size_t)(q0 + l31)*HD_ + ks*16 + hi*8]);

  f32x16 O[4];
  #pragma unroll
  for (int nb=0; nb<4; nb++)
    #pragma unroll
    for (int i=0;i<16;i++) O[nb][i] = 0.f;
  float m_ = -__builtin_inff();
  float l_ = 0.f;

  for (int kt = w; kt < KT; kt += 4) {
    const u16* Kt = Kfb + (size_t)kt*8192;
    // S^T[key][q]: key = kt*64 + 32n + (reg&3)+8*(reg>>2)+4*hi, q = q0+l31
    f32x16 s[2];
    #pragma unroll
    for (int n=0;n<2;n++)
      #pragma unroll
      for (int i=0;i<16;i++) s[n][i] = 0.f;
    __builtin_amdgcn_s_setprio(1);
    #pragma unroll
    for (int ks=0;ks<8;ks++)
      #pragma unroll
      for (int n=0;n<2;n++){
        short8 ka = *reinterpret_cast<const short8*>(Kt + (n*8 + ks)*512);
        s[n] = __builtin_amdgcn_mfma_f32_32x32x16_bf16(ka, qf[ks], s[n], 0, 0, 0);
      }
    __builtin_amdgcn_s_setprio(0);

    // causal mask (diagonal tile only; scale folded into Q)
    if (kt == KT-1) {
      #pragma unroll
      for (int n=0;n<2;n++)
        #pragma unroll
        for (int reg=0;reg<16;reg++){
          int key = kt*64 + n*32 + (reg&3) + 8*(reg>>2) + 4*hi;
          if (key > q0 + l31) s[n][reg] = -__builtin_inff();
        }
    }

    // row stats for q = l31 (in-reg tree + 1 shfl stage)
    float pmax = s[0][0];
    #pragma unroll
    for (int n=0;n<2;n++)
      #pragma unroll
      for (int reg=0;reg<16;reg++) pmax = fmaxf(pmax, s[n][reg]);
    pmax = fmaxf(pmax, __shfl_xor(pmax, 32, 64));

    // defer-max: skip rescale when growth <= 8
    if (!__all(pmax <= m_ + 8.f)) {
      float mnew = fmaxf(m_, pmax);
      float alpha = __expf(m_ - mnew);
      m_ = mnew;
      l_ *= alpha;
      #pragma unroll
      for (int nb=0; nb<4; nb++)
        #pragma unroll
        for (int i=0;i<16;i++) O[nb][i] *= alpha;
    }

    float rsum = 0.f;
    #pragma unroll
    for (int n=0;n<2;n++)
      #pragma unroll
      for (int reg=0;reg<16;reg++){
        float p = __expf(s[n][reg] - m_);
        s[n][reg] = p;
        rsum += p;
      }
    rsum += __shfl_xor(rsum, 32, 64);
    l_ += rsum;

    // pack P to bf16 pairs
    unsigned c[2][8], ox[2][8];
    #pragma unroll
    for (int n=0;n<2;n++)
      #pragma unroll
      for (int i=0;i<8;i++)
        c[n][i] = cvtpk_bf16(s[n][2*i], s[n][2*i+1]);
    #pragma unroll
    for (int n=0;n<2;n++)
      #pragma unroll
      for (int i=0;i<8;i++)
        ox[n][i] = (unsigned)__shfl_xor((int)c[n][i], 32, 64);

    // build P^T B-frags: pb[ks] holds P[q=l31][16ks + 8hi + 0..7]
    short8 pb[4];
    #pragma unroll
    for (int n=0;n<2;n++)
      #pragma unroll
      for (int sB=0;sB<2;sB++){
        union { u32x4 u; short8 s8; } t;
        t.u[0] = hi ? ox[n][4*sB+2] : c[n][4*sB+0];
        t.u[1] = hi ? ox[n][4*sB+3] : c[n][4*sB+1];
        t.u[2] = hi ? c[n][4*sB+2]  : ox[n][4*sB+0];
        t.u[3] = hi ? c[n][4*sB+3]  : ox[n][4*sB+1];
        pb[2*n+sB] = t.s8;
      }

    // PV: O^T[d][q] += V^T[d][k] P^T[k][q]
    const u16* Vt2 = Vfb + (size_t)kt*8192;
    __builtin_amdgcn_s_setprio(1);
    #pragma unroll
    for (int ks=0; ks<4; ks++){
      #pragma unroll
      for (int nb=0; nb<4; nb++){
        short8 av = *reinterpret_cast<const short8*>(Vt2 + (ks*4 + nb)*512);
        O[nb] = __builtin_amdgcn_mfma_f32_32x32x16_bf16(av, pb[ks], O[nb], 0, 0, 0);
      }
    }
    __builtin_amdgcn_s_setprio(0);
  }

  // publish partials
  if (hi == 0) { Ml[w][l31] = m_; Ll[w][l31] = l_; }
  #pragma unroll
  for (int nb=0; nb<4; nb++)
    #pragma unroll
    for (int g=0; g<4; g++){
      f32x4 v;
      v[0]=O[nb][4*g+0]; v[1]=O[nb][4*g+1]; v[2]=O[nb][4*g+2]; v[3]=O[nb][4*g+3];
      *reinterpret_cast<f32x4*>(&Ol[w][l31][nb*32 + g*8 + hi*4]) = v;
    }
  __syncthreads();

  // merge 4 key-split partials; thread -> (q, 16 d)
  {
    int q  = tid >> 3;
    int dc = (tid & 7) * 16;
    float mw[4], lw[4];
    float M = -__builtin_inff();
    #pragma unroll
    for (int w2=0; w2<4; w2++){ mw[w2]=Ml[w2][q]; lw[w2]=Ll[w2][q]; M = fmaxf(M, mw[w2]); }
    float den = 0.f, cw[4];
    #pragma unroll
    for (int w2=0; w2<4; w2++){ float e = __expf(mw[w2]-M); cw[w2]=e; den += lw[w2]*e; }
    float inv = 1.0f/den;
    float o[16];
    #pragma unroll
    for (int j=0;j<16;j++) o[j] = 0.f;
    #pragma unroll
    for (int w2=0; w2<4; w2++){
      #pragma unroll
      for (int g=0; g<4; g++){
        f32x4 p = *reinterpret_cast<const f32x4*>(&Ol[w2][q][dc + g*4]);
        #pragma unroll
        for (int j=0;j<4;j++) o[g*4+j] += cw[w2]*p[j];
      }
    }
    short8 st0, st1;
    #pragma unroll
    for (int j=0;j<8;j++){ st0[j] = (short)f2bf(o[j]*inv); st1[j] = (short)f2bf(o[8+j]*inv); }
    u16* dst = &AO[((size_t)b*L_ + q0 + q)*HD_ + dc];
    *reinterpret_cast<short8*>(dst)     = st0;
    *reinterpret_cast<short8*>(dst + 8) = st1;
  }
}

// ---------------- output projection ----------------
__global__ __launch_bounds__(256) void proj_kernel(
    const u16* __restrict__ AO, const u16* __restrict__ Wt_o,
    const float* __restrict__ bo, float* __restrict__ out)
{
  const int nb = blockIdx.x;   // 0..15
  const int rb = blockIdx.y;   // 0..127
  const int tid = threadIdx.x, lane = tid & 63, w = tid >> 6;
  const int wr = w >> 1, wc = w & 1;
  const int l15 = lane & 15, lhi = lane >> 4;
  const int row0 = rb * 128, n0 = nb * 128;

  __shared__ u16 Al[128][136];
  __shared__ u16 Bl[128][136];

  #pragma unroll
  for (int i=0;i<8;i++){
    int chunk = i*256 + tid;
    int r = chunk >> 4;
    int c = (chunk & 15) * 8;
    *reinterpret_cast<short8*>(&Al[r][c]) =
        *reinterpret_cast<const short8*>(&AO[(size_t)(row0+r)*HD_ + c]);
    *reinterpret_cast<short8*>(&Bl[r][c]) =
        *reinterpret_cast<const short8*>(&Wt_o[(size_t)(n0+r)*HD_ + c]);
  }
  __syncthreads();

  f32x4 acc[4][4];
  f32x4 zero4 = {0.f,0.f,0.f,0.f};
  for (int m=0;m<4;m++) for (int n=0;n<4;n++) acc[m][n] = zero4;

  #pragma unroll
  for (int ks=0; ks<128; ks+=32){
    short8 fa[4], fb[4];
    #pragma unroll
    for (int m=0;m<4;m++)
      fa[m] = *reinterpret_cast<const short8*>(&Al[wr*64 + m*16 + l15][ks + (lhi<<3)]);
    #pragma unroll
    for (int n=0;n<4;n++)
      fb[n] = *reinterpret_cast<const short8*>(&Bl[wc*64 + n*16 + l15][ks + (lhi<<3)]);
    #pragma unroll
    for (int m=0;m<4;m++)
      #pragma unroll
      for (int n=0;n<4;n++)
        acc[m][n] = __builtin_amdgcn_mfma_f32_16x16x32_bf16(fa[m], fb[n], acc[m][n], 0, 0, 0);
  }

  #pragma unroll
  for (int n=0;n<4;n++){
    int col = n0 + wc*64 + n*16 + l15;
    float b = bo[col];
    #pragma unroll
    for (int m=0;m<4;m++){
      #pragma unroll
      for (int r=0;r<4;r++){
        int row = row0 + wr*64 + m*16 + (lhi<<2) + r;
        out[(size_t)row*D_ + col] = acc[m][n][r] + b;
      }
    }
  }
}

// ---------------- launch ----------------
extern "C" void kernel_launch(void* const* d_in, const int* in_sizes, int n_in,
                              void* d_out, int out_size, void* d_ws, size_t ws_size,
                              hipStream_t stream) {
  const float* x  = (const float*)d_in[0];
  const float* Wq = (const float*)d_in[1];
  const float* bq = (const float*)d_in[2];
  const float* Wk = (const float*)d_in[3];
  const float* bk = (const float*)d_in[4];
  const float* Wv = (const float*)d_in[5];
  const float* bv = (const float*)d_in[6];
  const float* Wo = (const float*)d_in[7];
  const float* bo = (const float*)d_in[8];
  float* out = (float*)d_out;

  u16* ws      = (u16*)d_ws;
  u16* Wt_qkv  = ws;                            // [384][2048]
  u16* Wt_o    = Wt_qkv + 3*HD_*D_;             // [2048][128]
  u16* Q       = Wt_o   + (size_t)D_*HD_;       // [B*L][128] (pre-scaled)
  u16* Kf      = Q + (size_t)M_*HD_;            // [B][64][2][8][64][8] frag-major
  u16* Vf      = Kf + (size_t)M_*HD_;           // [B][64][4][4][64][8] frag-major
  u16* AO      = Vf + (size_t)M_*HD_;           // [B*L][128]

  prep_kernel<<<256, 256, 0, stream>>>(Wq, Wk, Wv, Wo, Wt_qkv, Wt_o);
  qkv_kernel<<<256, 512, 0, stream>>>(x, Wt_qkv, bq, bk, bv, Q, Kf, Vf);
  attn_kernel<<<512, 256, 0, stream>>>(Q, Kf, Vf, AO);
  proj_kernel<<<dim3(16, 128), 256, 0, stream>>>(AO, Wt_o, bo, out);
}

// Round 8
// 158.270 us; speedup vs baseline: 1.5427x; 1.0684x over previous
//
#include <hip/hip_runtime.h>

#define B_  4
#define L_  4096
#define D_  2048
#define HD_ 128
#define M_  (B_*L_)   // 16384

typedef __attribute__((ext_vector_type(8))) short short8;
typedef __attribute__((ext_vector_type(4))) float f32x4;
typedef __attribute__((ext_vector_type(16))) float f32x16;
typedef __attribute__((ext_vector_type(4))) unsigned short u16x4;
typedef __attribute__((ext_vector_type(4))) unsigned int u32x4;
typedef unsigned short u16;

#define GLL16(g, l) __builtin_amdgcn_global_load_lds( \
    (const __attribute__((address_space(1))) void*)(g), \
    (__attribute__((address_space(3))) void*)(l), 16, 0, 0)

__device__ __forceinline__ u16 f2bf(float f){
  union { float f; unsigned u; } v; v.f = f;
  unsigned r = v.u + 0x7FFFu + ((v.u >> 16) & 1u);
  return (u16)(r >> 16);
}

__device__ __forceinline__ unsigned cvtpk_bf16(float a, float b){
  unsigned r;
  asm volatile("v_cvt_pk_bf16_f32 %0, %1, %2" : "=v"(r) : "v"(a), "v"(b));
  return r;
}

// ---------------- prep: weight transposes to bf16 (weights only) ----------
__global__ __launch_bounds__(256) void prep_kernel(
    const float* __restrict__ Wq, const float* __restrict__ Wk,
    const float* __restrict__ Wv, const float* __restrict__ Wo,
    u16* __restrict__ Wt_qkv, u16* __restrict__ Wt_o)
{
  __shared__ float T[64][68];
  const int tid = threadIdx.x;
  int tb = blockIdx.x;                 // 0..255
  int mat = tb >> 6, t = tb & 63;
  const float* src; u16* dst; int Rw, Cw, rt, ct;
  if (mat < 3) {
    src = (mat==0) ? Wq : (mat==1) ? Wk : Wv;
    dst = Wt_qkv + (size_t)mat*HD_*D_;
    Rw = D_; Cw = HD_; rt = t >> 1; ct = t & 1;
  } else {
    src = Wo; dst = Wt_o;
    Rw = HD_; Cw = D_; rt = t >> 5; ct = t & 31;
  }
  int r0 = rt*64, c0 = ct*64;
  #pragma unroll
  for (int i=0;i<4;i++){
    int fid = i*256 + tid;
    int row = fid >> 4, c4 = (fid & 15) * 4;
    float4 v = *reinterpret_cast<const float4*>(src + (size_t)(r0+row)*Cw + c0 + c4);
    *reinterpret_cast<float4*>(&T[row][c4]) = v;
  }
  __syncthreads();
  #pragma unroll
  for (int i=0;i<2;i++){
    int sid = i*256 + tid;
    int crow = sid >> 3, k8 = (sid & 7) * 8;
    short8 o;
    #pragma unroll
    for (int j=0;j<8;j++) o[j] = (short)f2bf(T[k8+j][crow]);
    *reinterpret_cast<short8*>(dst + (size_t)(c0+crow)*Rw + r0 + k8) = o;
  }
}

// ---------------- fused QKV GEMM: 2-phase dbuf pipeline --------------------
// grid 256 (1 block/CU), 512 thr = 8 waves (2r x 4c), tile 64 x 384, BK=64.
// Per step: issue x(t+2)->regs, GLL16 B(t+1)->buf^1, compute(t),
// cvt+ds_write A(t+1), ONE barrier. Staging hides under compute (T3/T14).
// Q pre-scaled by 1/sqrt(HD). K/V written in attn fragment-major layouts:
//   Kf[b][kt][n][ks][lane][8], Vf[b][kt][ks][nb][lane][8].
__global__ __launch_bounds__(512, 2) void qkv_kernel(
    const float* __restrict__ x, const u16* __restrict__ Wt,
    const float* __restrict__ bq, const float* __restrict__ bk,
    const float* __restrict__ bv,
    u16* __restrict__ Q, u16* __restrict__ Kf, u16* __restrict__ Vf)
{
  const int rb = blockIdx.x;          // 0..255
  const int tid  = threadIdx.x;
  const int lane = tid & 63, w = tid >> 6;
  const int wr = w >> 2, wc = w & 3;
  const int l15 = lane & 15, lhi = lane >> 4;
  const int row0 = rb * 64;

  __shared__ u16 Asm[2][64*64];       // x tile bf16, swizzled, double-buffered
  __shared__ u16 Bsm[2][384*64];      // Wqkv^T tile, swizzled, double-buffered

  // B staging: 6 GLL16 per wave per step; source pre-swizzled, dest linear
  const u16* bSrc[6]; int bDstOff[6];
  #pragma unroll
  for (int i=0;i<6;i++){
    int id = i*512 + w*64 + lane;
    int r = id >> 3, c = (id & 7) * 8;
    bSrc[i] = Wt + (size_t)r*D_ + (c ^ ((r&7)*8));
    bDstOff[i] = i*4096 + w*512;
  }
  // A staging: 1 short8/thread/step
  const int ar = tid >> 3, ac = (tid & 7) * 8;
  const int aoff = ar*64 + (ac ^ ((ar&7)*8));
  const float* xrow = x + (size_t)(row0+ar)*D_ + ac;

  // frag read offsets (swizzle-matched)
  int offA[2][2], offB[2][6];
  #pragma unroll
  for (int ks=0;ks<2;ks++){
    #pragma unroll
    for (int m=0;m<2;m++){
      int rA = wr*32 + m*16 + l15;
      offA[ks][m] = rA*64 + ((ks*32 + lhi*8) ^ ((rA&7)*8));
    }
    #pragma unroll
    for (int n=0;n<6;n++){
      int rB = wc*96 + n*16 + l15;
      offB[ks][n] = rB*64 + ((ks*32 + lhi*8) ^ ((rB&7)*8));
    }
  }

  f32x4 acc[2][6];
  f32x4 zero4 = {0.f,0.f,0.f,0.f};
  #pragma unroll
  for (int m=0;m<2;m++)
    #pragma unroll
    for (int n=0;n<6;n++) acc[m][n] = zero4;

  // prologue: tile 0 -> buf 0; x tile 1 -> regs (depth-2 pipeline)
  float4 xa0 = *reinterpret_cast<const float4*>(xrow);
  float4 xa1 = *reinterpret_cast<const float4*>(xrow + 4);
  #pragma unroll
  for (int i=0;i<6;i++){ GLL16(bSrc[i], &Bsm[0][bDstOff[i]]); bSrc[i] += 64; }
  {
    short8 a8;
    a8[0]=(short)f2bf(xa0.x); a8[1]=(short)f2bf(xa0.y);
    a8[2]=(short)f2bf(xa0.z); a8[3]=(short)f2bf(xa0.w);
    a8[4]=(short)f2bf(xa1.x); a8[5]=(short)f2bf(xa1.y);
    a8[6]=(short)f2bf(xa1.z); a8[7]=(short)f2bf(xa1.w);
    *reinterpret_cast<short8*>(&Asm[0][aoff]) = a8;
  }
  xa0 = *reinterpret_cast<const float4*>(xrow + 64);
  xa1 = *reinterpret_cast<const float4*>(xrow + 68);
  __syncthreads();   // drains GLL16 (tile0) + A ds_write

  for (int t = 0; t < 32; ++t) {
    const int cur = t & 1, nxt = cur ^ 1;
    const bool more = (t + 1 < 32);
    // (1) issue x loads for tile t+2 (consumed end of next iter: ~2 phases cover)
    float4 xb0, xb1;
    if (t + 2 < 32) {
      const float* xp = xrow + (t+2)*64;
      xb0 = *reinterpret_cast<const float4*>(xp);
      xb1 = *reinterpret_cast<const float4*>(xp + 4);
    }
    // (2) issue B staging for tile t+1 (covered by compute below)
    if (more) {
      #pragma unroll
      for (int i=0;i<6;i++){ GLL16(bSrc[i], &Bsm[nxt][bDstOff[i]]); bSrc[i] += 64; }
    }
    // (3) compute tile t
    const u16* Ac = &Asm[cur][0];
    const u16* Bc = &Bsm[cur][0];
    #pragma unroll
    for (int ks=0;ks<2;ks++){
      short8 fa[2], fb[6];
      #pragma unroll
      for (int m=0;m<2;m++) fa[m] = *reinterpret_cast<const short8*>(Ac + offA[ks][m]);
      #pragma unroll
      for (int n=0;n<6;n++) fb[n] = *reinterpret_cast<const short8*>(Bc + offB[ks][n]);
      #pragma unroll
      for (int m=0;m<2;m++)
        #pragma unroll
        for (int n=0;n<6;n++)
          acc[m][n] = __builtin_amdgcn_mfma_f32_16x16x32_bf16(fa[m], fb[n], acc[m][n], 0, 0, 0);
    }
    // (4) write A(t+1) from regs loaded last iteration
    if (more) {
      short8 a8;
      a8[0]=(short)f2bf(xa0.x); a8[1]=(short)f2bf(xa0.y);
      a8[2]=(short)f2bf(xa0.z); a8[3]=(short)f2bf(xa0.w);
      a8[4]=(short)f2bf(xa1.x); a8[5]=(short)f2bf(xa1.y);
      a8[6]=(short)f2bf(xa1.z); a8[7]=(short)f2bf(xa1.w);
      *reinterpret_cast<short8*>(&Asm[nxt][aoff]) = a8;
    }
    // (5) one barrier per step (drains this step's GLL16 + ds_write)
    __syncthreads();
    xa0 = xb0; xa1 = xb1;
  }

  const float qscale = 0.08838834764831845f;  // 1/sqrt(128)
  #pragma unroll
  for (int n=0;n<6;n++){
    int col = wc*96 + n*16 + l15;
    int j = col >> 7;            // 0:Q 1:K 2:V
    int c = col & 127;
    float bi = (j==0) ? bq[c] : (j==1) ? bk[c] : bv[c];
    #pragma unroll
    for (int m=0;m<2;m++){
      int rowb = row0 + wr*32 + m*16 + (lhi<<2);
      int bb = rowb >> 12;
      int l0 = rowb & (L_-1);
      if (j == 0) {
        #pragma unroll
        for (int r=0;r<4;r++)
          Q[(size_t)(rowb+r)*HD_ + c] = f2bf((acc[m][n][r] + bi) * qscale);
      } else if (j == 1) {
        // Kf: d=c fixed -> ks,hi,j fixed; key varies -> lane varies
        int ksd = c >> 4, hid = (c >> 3) & 1, jd = c & 7;
        #pragma unroll
        for (int r=0;r<4;r++){
          int l = l0 + r;
          int kt = l >> 6, k6 = l & 63;
          int n2 = k6 >> 5, l31k = k6 & 31;
          Kf[((size_t)bb*64 + kt)*8192 + (n2*8 + ksd)*512 + (hid*32 + l31k)*8 + jd]
              = f2bf(acc[m][n][r] + bi);
        }
      } else {
        // Vf: d=c fixed -> nb,l31 fixed; keys r=0..3 share one 8B chunk
        int nbv = (c >> 5) & 3, l31v = c & 31;
        int kt = l0 >> 6, k6 = l0 & 63;
        int ksv = k6 >> 4, hiv = (k6 >> 3) & 1, j0 = k6 & 7;
        u16x4 v4;
        #pragma unroll
        for (int r=0;r<4;r++) v4[r] = f2bf(acc[m][n][r] + bi);
        *reinterpret_cast<u16x4*>(
            Vf + ((size_t)bb*64 + kt)*8192 + (ksv*4 + nbv)*512 + (hiv*32 + l31v)*8 + j0) = v4;
      }
    }
  }
}

// ---------------- flash attention: 32x32 swapped-QK^T, frag-major K/V ------
// grid 512 (2/CU): block = 32 q-rows; 4 waves key-split (kt = w mod 4).
// All per-iter loads are lane-contiguous 1KB chunks (Kf/Vf layouts).
__global__ __launch_bounds__(256, 2) void attn_kernel(
    const u16* __restrict__ Qg, const u16* __restrict__ Kfg,
    const u16* __restrict__ Vfg, u16* __restrict__ AO)
{
  const int blk = blockIdx.x;
  const int xcd = blk & 7;
  const int sub = blk >> 3;                    // 0..63
  const int b   = xcd >> 1;                    // batch -> XCD pair
  const int strip = 127 - (2*sub + (xcd & 1)); // long strips dispatch first
  const int q0  = strip * 32;
  const int KT  = (strip >> 1) + 1;            // #64-key tiles

  const int tid = threadIdx.x, lane = tid & 63, w = tid >> 6;
  const int l31 = lane & 31;
  const int hi  = lane >> 5;

  const u16* Qb  = Qg  + (size_t)b * L_ * HD_;
  const u16* Kfb = Kfg + (size_t)b * 64 * 8192 + lane*8;
  const u16* Vfb = Vfg + (size_t)b * 64 * 8192 + lane*8;

  __shared__ __attribute__((aligned(16))) float Ol[4][32][132];
  __shared__ float Ml[4][32], Ll[4][32];

  // Q B-frags: qf[ks] = Q[q0+l31][ks*16 + 8hi .. +8] (Q pre-scaled)
  short8 qf[8];
  #pragma unroll
  for (int ks=0; ks<8; ks++)
    qf[ks] = *reinterpret_cast<const short8*>(
        &Qb[(size_t)(q0 + l31)*HD_ + ks*16 + hi*8]);

  f32x16 O[4];
  #pragma unroll
  for (int nb=0; nb<4; nb++)
    #pragma unroll
    for (int i=0;i<16;i++) O[nb][i] = 0.f;
  float m_ = -__builtin_inff();
  float l_ = 0.f;

  for (int kt = w; kt < KT; kt += 4) {
    const u16* Kt = Kfb + (size_t)kt*8192;
    // S^T[key][q]: key = kt*64 + 32n + (reg&3)+8*(reg>>2)+4*hi, q = q0+l31
    f32x16 s[2];
    #pragma unroll
    for (int n=0;n<2;n++)
      #pragma unroll
      for (int i=0;i<16;i++) s[n][i] = 0.f;
    __builtin_amdgcn_s_setprio(1);
    #pragma unroll
    for (int ks=0;ks<8;ks++)
      #pragma unroll
      for (int n=0;n<2;n++){
        short8 ka = *reinterpret_cast<const short8*>(Kt + (n*8 + ks)*512);
        s[n] = __builtin_amdgcn_mfma_f32_32x32x16_bf16(ka, qf[ks], s[n], 0, 0, 0);
      }
    __builtin_amdgcn_s_setprio(0);

    // causal mask (diagonal tile only; scale folded into Q)
    if (kt == KT-1) {
      #pragma unroll
      for (int n=0;n<2;n++)
        #pragma unroll
        for (int reg=0;reg<16;reg++){
          int key = kt*64 + n*32 + (reg&3) + 8*(reg>>2) + 4*hi;
          if (key > q0 + l31) s[n][reg] = -__builtin_inff();
        }
    }

    // row stats for q = l31 (in-reg tree + 1 shfl stage)
    float pmax = s[0][0];
    #pragma unroll
    for (int n=0;n<2;n++)
      #pragma unroll
      for (int reg=0;reg<16;reg++) pmax = fmaxf(pmax, s[n][reg]);
    pmax = fmaxf(pmax, __shfl_xor(pmax, 32, 64));

    // defer-max: skip rescale when growth <= 8
    if (!__all(pmax <= m_ + 8.f)) {
      float mnew = fmaxf(m_, pmax);
      float alpha = __expf(m_ - mnew);
      m_ = mnew;
      l_ *= alpha;
      #pragma unroll
      for (int nb=0; nb<4; nb++)
        #pragma unroll
        for (int i=0;i<16;i++) O[nb][i] *= alpha;
    }

    float rsum = 0.f;
    #pragma unroll
    for (int n=0;n<2;n++)
      #pragma unroll
      for (int reg=0;reg<16;reg++){
        float p = __expf(s[n][reg] - m_);
        s[n][reg] = p;
        rsum += p;
      }
    rsum += __shfl_xor(rsum, 32, 64);
    l_ += rsum;

    // pack P to bf16 pairs
    unsigned c[2][8], ox[2][8];
    #pragma unroll
    for (int n=0;n<2;n++)
      #pragma unroll
      for (int i=0;i<8;i++)
        c[n][i] = cvtpk_bf16(s[n][2*i], s[n][2*i+1]);
    #pragma unroll
    for (int n=0;n<2;n++)
      #pragma unroll
      for (int i=0;i<8;i++)
        ox[n][i] = (unsigned)__shfl_xor((int)c[n][i], 32, 64);

    // build P^T B-frags: pb[ks] holds P[q=l31][16ks + 8hi + 0..7]
    short8 pb[4];
    #pragma unroll
    for (int n=0;n<2;n++)
      #pragma unroll
      for (int sB=0;sB<2;sB++){
        union { u32x4 u; short8 s8; } t;
        t.u[0] = hi ? ox[n][4*sB+2] : c[n][4*sB+0];
        t.u[1] = hi ? ox[n][4*sB+3] : c[n][4*sB+1];
        t.u[2] = hi ? c[n][4*sB+2]  : ox[n][4*sB+0];
        t.u[3] = hi ? c[n][4*sB+3]  : ox[n][4*sB+1];
        pb[2*n+sB] = t.s8;
      }

    // PV: O^T[d][q] += V^T[d][k] P^T[k][q]
    const u16* Vt2 = Vfb + (size_t)kt*8192;
    __builtin_amdgcn_s_setprio(1);
    #pragma unroll
    for (int ks=0; ks<4; ks++){
      #pragma unroll
      for (int nb=0; nb<4; nb++){
        short8 av = *reinterpret_cast<const short8*>(Vt2 + (ks*4 + nb)*512);
        O[nb] = __builtin_amdgcn_mfma_f32_32x32x16_bf16(av, pb[ks], O[nb], 0, 0, 0);
      }
    }
    __builtin_amdgcn_s_setprio(0);
  }

  // publish partials
  if (hi == 0) { Ml[w][l31] = m_; Ll[w][l31] = l_; }
  #pragma unroll
  for (int nb=0; nb<4; nb++)
    #pragma unroll
    for (int g=0; g<4; g++){
      f32x4 v;
      v[0]=O[nb][4*g+0]; v[1]=O[nb][4*g+1]; v[2]=O[nb][4*g+2]; v[3]=O[nb][4*g+3];
      *reinterpret_cast<f32x4*>(&Ol[w][l31][nb*32 + g*8 + hi*4]) = v;
    }
  __syncthreads();

  // merge 4 key-split partials; thread -> (q, 16 d)
  {
    int q  = tid >> 3;
    int dc = (tid & 7) * 16;
    float mw[4], lw[4];
    float M = -__builtin_inff();
    #pragma unroll
    for (int w2=0; w2<4; w2++){ mw[w2]=Ml[w2][q]; lw[w2]=Ll[w2][q]; M = fmaxf(M, mw[w2]); }
    float den = 0.f, cw[4];
    #pragma unroll
    for (int w2=0; w2<4; w2++){ float e = __expf(mw[w2]-M); cw[w2]=e; den += lw[w2]*e; }
    float inv = 1.0f/den;
    float o[16];
    #pragma unroll
    for (int j=0;j<16;j++) o[j] = 0.f;
    #pragma unroll
    for (int w2=0; w2<4; w2++){
      #pragma unroll
      for (int g=0; g<4; g++){
        f32x4 p = *reinterpret_cast<const f32x4*>(&Ol[w2][q][dc + g*4]);
        #pragma unroll
        for (int j=0;j<4;j++) o[g*4+j] += cw[w2]*p[j];
      }
    }
    short8 st0, st1;
    #pragma unroll
    for (int j=0;j<8;j++){ st0[j] = (short)f2bf(o[j]*inv); st1[j] = (short)f2bf(o[8+j]*inv); }
    u16* dst = &AO[((size_t)b*L_ + q0 + q)*HD_ + dc];
    *reinterpret_cast<short8*>(dst)     = st0;
    *reinterpret_cast<short8*>(dst + 8) = st1;
  }
}

// ---------------- output projection ----------------
__global__ __launch_bounds__(256) void proj_kernel(
    const u16* __restrict__ AO, const u16* __restrict__ Wt_o,
    const float* __restrict__ bo, float* __restrict__ out)
{
  const int nb = blockIdx.x;   // 0..15
  const int rb = blockIdx.y;   // 0..127
  const int tid = threadIdx.x, lane = tid & 63, w = tid >> 6;
  const int wr = w >> 1, wc = w & 1;
  const int l15 = lane & 15, lhi = lane >> 4;
  const int row0 = rb * 128, n0 = nb * 128;

  __shared__ u16 Al[128][136];
  __shared__ u16 Bl[128][136];

  #pragma unroll
  for (int i=0;i<8;i++){
    int chunk = i*256 + tid;
    int r = chunk >> 4;
    int c = (chunk & 15) * 8;
    *reinterpret_cast<short8*>(&Al[r][c]) =
        *reinterpret_cast<const short8*>(&AO[(size_t)(row0+r)*HD_ + c]);
    *reinterpret_cast<short8*>(&Bl[r][c]) =
        *reinterpret_cast<const short8*>(&Wt_o[(size_t)(n0+r)*HD_ + c]);
  }
  __syncthreads();

  f32x4 acc[4][4];
  f32x4 zero4 = {0.f,0.f,0.f,0.f};
  for (int m=0;m<4;m++) for (int n=0;n<4;n++) acc[m][n] = zero4;

  #pragma unroll
  for (int ks=0; ks<128; ks+=32){
    short8 fa[4], fb[4];
    #pragma unroll
    for (int m=0;m<4;m++)
      fa[m] = *reinterpret_cast<const short8*>(&Al[wr*64 + m*16 + l15][ks + (lhi<<3)]);
    #pragma unroll
    for (int n=0;n<4;n++)
      fb[n] = *reinterpret_cast<const short8*>(&Bl[wc*64 + n*16 + l15][ks + (lhi<<3)]);
    #pragma unroll
    for (int m=0;m<4;m++)
      #pragma unroll
      for (int n=0;n<4;n++)
        acc[m][n] = __builtin_amdgcn_mfma_f32_16x16x32_bf16(fa[m], fb[n], acc[m][n], 0, 0, 0);
  }

  #pragma unroll
  for (int n=0;n<4;n++){
    int col = n0 + wc*64 + n*16 + l15;
    float b = bo[col];
    #pragma unroll
    for (int m=0;m<4;m++){
      #pragma unroll
      for (int r=0;r<4;r++){
        int row = row0 + wr*64 + m*16 + (lhi<<2) + r;
        out[(size_t)row*D_ + col] = acc[m][n][r] + b;
      }
    }
  }
}

// ---------------- launch ----------------
extern "C" void kernel_launch(void* const* d_in, const int* in_sizes, int n_in,
                              void* d_out, int out_size, void* d_ws, size_t ws_size,
                              hipStream_t stream) {
  const float* x  = (const float*)d_in[0];
  const float* Wq = (const float*)d_in[1];
  const float* bq = (const float*)d_in[2];
  const float* Wk = (const float*)d_in[3];
  const float* bk = (const float*)d_in[4];
  const float* Wv = (const float*)d_in[5];
  const float* bv = (const float*)d_in[6];
  const float* Wo = (const float*)d_in[7];
  const float* bo = (const float*)d_in[8];
  float* out = (float*)d_out;

  u16* ws      = (u16*)d_ws;
  u16* Wt_qkv  = ws;                            // [384][2048]
  u16* Wt_o    = Wt_qkv + 3*HD_*D_;             // [2048][128]
  u16* Q       = Wt_o   + (size_t)D_*HD_;       // [B*L][128] (pre-scaled)
  u16* Kf      = Q + (size_t)M_*HD_;            // [B][64][2][8][64][8] frag-major
  u16* Vf      = Kf + (size_t)M_*HD_;           // [B][64][4][4][64][8] frag-major
  u16* AO      = Vf + (size_t)M_*HD_;           // [B*L][128]

  prep_kernel<<<256, 256, 0, stream>>>(Wq, Wk, Wv, Wo, Wt_qkv, Wt_o);
  qkv_kernel<<<256, 512, 0, stream>>>(x, Wt_qkv, bq, bk, bv, Q, Kf, Vf);
  attn_kernel<<<512, 256, 0, stream>>>(Q, Kf, Vf, AO);
  proj_kernel<<<dim3(16, 128), 256, 0, stream>>>(AO, Wt_o, bo, out);
}